// Round 1
// baseline (3327.387 us; speedup 1.0000x reference)
//
#include <hip/hip_runtime.h>
#include <math.h>

#define BB 2048
#define EMB 128
#define HID 512
#define G4 2048   // 4*HID
#define VT 8000
#define NSTEP 9
#define NT 125    // VT/64

// ---------------- embedding gather ----------------
__global__ __launch_bounds__(256) void gather_kernel(
    float* __restrict__ X, const float* __restrict__ table,
    const int* __restrict__ idx, int stride, int offset)
{
    int t = blockIdx.x * 256 + threadIdx.x;   // BB*32 threads
    int row = t >> 5, c4 = (t & 31) << 2;
    int tok = idx[row * stride + offset];
    *(float4*)&X[row * EMB + c4] = *(const float4*)&table[tok * EMB + c4];
}

// ---------------- LSTM cell elementwise ----------------
__device__ __forceinline__ float sigm(float x) { return 1.0f / (1.0f + expf(-x)); }

__global__ __launch_bounds__(256) void cell_kernel(
    const float* __restrict__ gates, float* __restrict__ C, float* __restrict__ H)
{
    int t = blockIdx.x * 256 + threadIdx.x;   // BB*HID/4 threads
    int row = t >> 7, q4 = (t & 127) << 2;
    const float4 gi = *(const float4*)&gates[row * G4 + q4];
    const float4 gf = *(const float4*)&gates[row * G4 + 512 + q4];
    const float4 gg = *(const float4*)&gates[row * G4 + 1024 + q4];
    const float4 go = *(const float4*)&gates[row * G4 + 1536 + q4];
    float4 c = *(const float4*)&C[row * HID + q4];
    float4 h;
    float ci, cf, cg, co;

    ci = sigm(gi.x); cf = sigm(gf.x); cg = tanhf(gg.x); co = sigm(go.x);
    c.x = cf * c.x + ci * cg;  h.x = co * tanhf(c.x);
    ci = sigm(gi.y); cf = sigm(gf.y); cg = tanhf(gg.y); co = sigm(go.y);
    c.y = cf * c.y + ci * cg;  h.y = co * tanhf(c.y);
    ci = sigm(gi.z); cf = sigm(gf.z); cg = tanhf(gg.z); co = sigm(go.z);
    c.z = cf * c.z + ci * cg;  h.z = co * tanhf(c.z);
    ci = sigm(gi.w); cf = sigm(gf.w); cg = tanhf(gg.w); co = sigm(go.w);
    c.w = cf * c.w + ci * cg;  h.w = co * tanhf(c.w);

    *(float4*)&C[row * HID + q4] = c;
    *(float4*)&H[row * HID + q4] = h;
}

// ---------------- fp32 GEMM: C[M,N] = A·B^T (+bias), two K-segments ----------------
// mode 0: write Cout.  mode 1: d_out = logits (step 0).  mode 2: d_out = max(d_out, logits).
// modes 1/2 also emit per-64-col-tile argmax partials (first-index tie-break).
__global__ __launch_bounds__(256) void gemm_kernel(
    const float* __restrict__ A0, const float* __restrict__ B0, int K0,
    const float* __restrict__ A1, const float* __restrict__ B1, int K1,
    const float* __restrict__ bias0, const float* __restrict__ bias1,
    int N, int mode,
    float* __restrict__ Cout,
    float* __restrict__ outmax,
    float* __restrict__ partval, int* __restrict__ partidx)
{
    __shared__ float As[32 * 68];
    __shared__ float Bs[32 * 68];
    const int bj0 = blockIdx.x * 64;
    const int bi0 = blockIdx.y * 64;
    const int t = threadIdx.x;
    const int tr = t >> 4, tc = t & 15;

    float acc[4][4] = {};

    const float* Aseg[2] = {A0, A1};
    const float* Bseg[2] = {B0, B1};
    const int    Kseg[2] = {K0, K1};

    for (int s = 0; s < 2; ++s) {
        const float* __restrict__ A  = Aseg[s];
        const float* __restrict__ Bw = Bseg[s];
        const int K = Kseg[s];
        if (K == 0) continue;
        for (int ch = 0; ch < K; ch += 32) {
            // stage 64x32 A-tile and B-tile, transposed to [k][row], row stride 68
            #pragma unroll
            for (int rep = 0; rep < 2; ++rep) {
                int li = t + rep * 256;           // 0..511
                int row = li >> 3, k4 = (li & 7) << 2;
                float4 va = *(const float4*)&A[(size_t)(bi0 + row) * K + ch + k4];
                float4 vb = *(const float4*)&Bw[(size_t)(bj0 + row) * K + ch + k4];
                As[(k4 + 0) * 68 + row] = va.x; As[(k4 + 1) * 68 + row] = va.y;
                As[(k4 + 2) * 68 + row] = va.z; As[(k4 + 3) * 68 + row] = va.w;
                Bs[(k4 + 0) * 68 + row] = vb.x; Bs[(k4 + 1) * 68 + row] = vb.y;
                Bs[(k4 + 2) * 68 + row] = vb.z; Bs[(k4 + 3) * 68 + row] = vb.w;
            }
            __syncthreads();
            #pragma unroll
            for (int k = 0; k < 32; ++k) {
                float4 a = *(const float4*)&As[k * 68 + tr * 4];
                float4 b = *(const float4*)&Bs[k * 68 + tc * 4];
                acc[0][0] += a.x * b.x; acc[0][1] += a.x * b.y; acc[0][2] += a.x * b.z; acc[0][3] += a.x * b.w;
                acc[1][0] += a.y * b.x; acc[1][1] += a.y * b.y; acc[1][2] += a.y * b.z; acc[1][3] += a.y * b.w;
                acc[2][0] += a.z * b.x; acc[2][1] += a.z * b.y; acc[2][2] += a.z * b.z; acc[2][3] += a.z * b.w;
                acc[3][0] += a.w * b.x; acc[3][1] += a.w * b.y; acc[3][2] += a.w * b.z; acc[3][3] += a.w * b.w;
            }
            __syncthreads();
        }
    }

    // bias
    float bcol[4];
    #pragma unroll
    for (int j = 0; j < 4; ++j) {
        int col = bj0 + tc * 4 + j;
        float bb = 0.0f;
        if (bias0) bb += bias0[col];
        if (bias1) bb += bias1[col];
        bcol[j] = bb;
    }
    #pragma unroll
    for (int i = 0; i < 4; ++i)
        #pragma unroll
        for (int j = 0; j < 4; ++j) acc[i][j] += bcol[j];

    if (mode == 0) {
        #pragma unroll
        for (int i = 0; i < 4; ++i) {
            float4 v = make_float4(acc[i][0], acc[i][1], acc[i][2], acc[i][3]);
            *(float4*)&Cout[(size_t)(bi0 + tr * 4 + i) * N + bj0 + tc * 4] = v;
        }
    } else {
        #pragma unroll
        for (int i = 0; i < 4; ++i) {
            int row = bi0 + tr * 4 + i;
            float4 v = make_float4(acc[i][0], acc[i][1], acc[i][2], acc[i][3]);
            float* op = &outmax[(size_t)row * VT + bj0 + tc * 4];
            if (mode == 2) {
                float4 o = *(const float4*)op;
                v.x = fmaxf(v.x, o.x); v.y = fmaxf(v.y, o.y);
                v.z = fmaxf(v.z, o.z); v.w = fmaxf(v.w, o.w);
            }
            *(float4*)op = v;

            // per-row argmax partial over this 64-col tile (use raw logits acc)
            float best = acc[i][0]; int bidx = bj0 + tc * 4;
            #pragma unroll
            for (int j = 1; j < 4; ++j)
                if (acc[i][j] > best) { best = acc[i][j]; bidx = bj0 + tc * 4 + j; }
            #pragma unroll
            for (int off = 1; off < 16; off <<= 1) {
                float ov = __shfl_xor(best, off, 64);
                int   oi = __shfl_xor(bidx, off, 64);
                if (ov > best || (ov == best && oi < bidx)) { best = ov; bidx = oi; }
            }
            if (tc == 0) {
                partval[(size_t)row * NT + blockIdx.x] = best;
                partidx[(size_t)row * NT + blockIdx.x] = bidx;
            }
        }
    }
}

// ---------------- argmax finalize: reduce NT partials per row ----------------
__global__ __launch_bounds__(128) void finalize_kernel(
    const float* __restrict__ partval, const int* __restrict__ partidx,
    int* __restrict__ tok)
{
    __shared__ float sv[128];
    __shared__ int   si[128];
    int row = blockIdx.x, t = threadIdx.x;
    float v = -INFINITY; int ix = 0x7fffffff;
    if (t < NT) { v = partval[(size_t)row * NT + t]; ix = partidx[(size_t)row * NT + t]; }
    sv[t] = v; si[t] = ix;
    __syncthreads();
    for (int s = 64; s > 0; s >>= 1) {
        if (t < s) {
            float ov = sv[t + s]; int oi = si[t + s];
            if (ov > sv[t] || (ov == sv[t] && oi < si[t])) { sv[t] = ov; si[t] = oi; }
        }
        __syncthreads();
    }
    if (t == 0) tok[row] = si[0];
}

extern "C" void kernel_launch(void* const* d_in, const int* in_sizes, int n_in,
                              void* d_out, int out_size, void* d_ws, size_t ws_size,
                              hipStream_t stream) {
    const int*   src       = (const int*)d_in[0];
    const float* src_embed = (const float*)d_in[1];
    const float* tgt_embed = (const float*)d_in[2];
    const float* enc_Wih   = (const float*)d_in[3];
    const float* enc_Whh   = (const float*)d_in[4];
    const float* enc_bih   = (const float*)d_in[5];
    const float* enc_bhh   = (const float*)d_in[6];
    const float* dec_Wih   = (const float*)d_in[7];
    const float* dec_Whh   = (const float*)d_in[8];
    const float* dec_bih   = (const float*)d_in[9];
    const float* dec_bhh   = (const float*)d_in[10];
    const float* proj_W    = (const float*)d_in[11];
    const float* proj_b    = (const float*)d_in[12];
    float* out = (float*)d_out;

    float* ws    = (float*)d_ws;
    float* X     = ws;                   // 262144 f
    float* H     = X + 262144;           // 1048576 f
    float* C     = H + 1048576;          // 1048576 f
    float* GATES = C + 1048576;          // 4194304 f
    float* PV    = GATES + 4194304;      // 256000 f
    int*   PI    = (int*)(PV + 256000);  // 256000 i
    int*   TOK   = PI + 256000;          // 2048 i

    hipMemsetAsync(H, 0, (size_t)1048576 * 4, stream);
    hipMemsetAsync(C, 0, (size_t)1048576 * 4, stream);
    hipMemsetAsync(TOK, 0, (size_t)2048 * 4, stream);   // BOS = 0

    dim3 ggate(G4 / 64, BB / 64);   // 32 x 32
    dim3 gproj(NT, BB / 64);        // 125 x 32

    // ---- encoder: 2 steps ----
    for (int tstep = 0; tstep < 2; ++tstep) {
        gather_kernel<<<256, 256, 0, stream>>>(X, src_embed, src, 2, tstep);
        gemm_kernel<<<ggate, 256, 0, stream>>>(X, enc_Wih, EMB, H, enc_Whh, HID,
            enc_bih, enc_bhh, G4, 0, GATES, nullptr, nullptr, nullptr);
        cell_kernel<<<1024, 256, 0, stream>>>(GATES, C, H);
    }

    // ---- decoder: 9 greedy steps ----
    for (int s = 0; s < NSTEP; ++s) {
        gather_kernel<<<256, 256, 0, stream>>>(X, tgt_embed, TOK, 1, 0);
        gemm_kernel<<<ggate, 256, 0, stream>>>(X, dec_Wih, EMB, H, dec_Whh, HID,
            dec_bih, dec_bhh, G4, 0, GATES, nullptr, nullptr, nullptr);
        cell_kernel<<<1024, 256, 0, stream>>>(GATES, C, H);
        gemm_kernel<<<gproj, 256, 0, stream>>>(H, proj_W, HID, nullptr, nullptr, 0,
            proj_b, nullptr, VT, (s == 0 ? 1 : 2), nullptr, out, PV, PI);
        if (s + 1 < NSTEP)
            finalize_kernel<<<BB, 128, 0, stream>>>(PV, PI, TOK);
    }
}

// Round 2
// 2084.388 us; speedup vs baseline: 1.5963x; 1.5963x over previous
//
#include <hip/hip_runtime.h>
#include <math.h>

#define BB 2048
#define EMB 128
#define HID 512
#define G4 2048   // 4*HID
#define VT 8000
#define VTP 8064  // padded to 63*128
#define NSTEP 9
#define NTILE 63  // col tiles of 128
#define NPART 126 // 63 tiles * 2 half-tiles (wc)
#define PSTRIDE 128

typedef short bf16x8 __attribute__((ext_vector_type(8)));
typedef float f32x4 __attribute__((ext_vector_type(4)));

__device__ __forceinline__ ushort f2bf(float x) {
    uint u = __float_as_uint(x);
    uint r = (u + 0x7fffu + ((u >> 16) & 1u)) >> 16;
    return (ushort)r;
}
__device__ __forceinline__ float bf2f(ushort h) {
    return __uint_as_float(((uint)h) << 16);
}

// ---------------- embedding gather ----------------
__global__ __launch_bounds__(256) void gather_kernel(
    float* __restrict__ X, const float* __restrict__ table,
    const int* __restrict__ idx, int stride, int offset)
{
    int t = blockIdx.x * 256 + threadIdx.x;   // BB*32 threads
    int row = t >> 5, c4 = (t & 31) << 2;
    int tok = idx[row * stride + offset];
    *(float4*)&X[row * EMB + c4] = *(const float4*)&table[tok * EMB + c4];
}

// ---------------- LSTM cell elementwise (+ bf16 hi/lo H emit) ----------------
__device__ __forceinline__ float sigm(float x) { return 1.0f / (1.0f + expf(-x)); }

__global__ __launch_bounds__(256) void cell_kernel(
    const float* __restrict__ gates, float* __restrict__ C, float* __restrict__ H,
    ushort* __restrict__ Hhi, ushort* __restrict__ Hlo)
{
    int t = blockIdx.x * 256 + threadIdx.x;   // BB*HID/4 threads
    int row = t >> 7, q4 = (t & 127) << 2;
    const float4 gi = *(const float4*)&gates[row * G4 + q4];
    const float4 gf = *(const float4*)&gates[row * G4 + 512 + q4];
    const float4 gg = *(const float4*)&gates[row * G4 + 1024 + q4];
    const float4 go = *(const float4*)&gates[row * G4 + 1536 + q4];
    float4 c = *(const float4*)&C[row * HID + q4];
    float4 h;
    float ci, cf, cg, co;

    ci = sigm(gi.x); cf = sigm(gf.x); cg = tanhf(gg.x); co = sigm(go.x);
    c.x = cf * c.x + ci * cg;  h.x = co * tanhf(c.x);
    ci = sigm(gi.y); cf = sigm(gf.y); cg = tanhf(gg.y); co = sigm(go.y);
    c.y = cf * c.y + ci * cg;  h.y = co * tanhf(c.y);
    ci = sigm(gi.z); cf = sigm(gf.z); cg = tanhf(gg.z); co = sigm(go.z);
    c.z = cf * c.z + ci * cg;  h.z = co * tanhf(c.z);
    ci = sigm(gi.w); cf = sigm(gf.w); cg = tanhf(gg.w); co = sigm(go.w);
    c.w = cf * c.w + ci * cg;  h.w = co * tanhf(c.w);

    *(float4*)&C[row * HID + q4] = c;
    *(float4*)&H[row * HID + q4] = h;

    ushort4 hh, hl;
    hh.x = f2bf(h.x); hl.x = f2bf(h.x - bf2f(hh.x));
    hh.y = f2bf(h.y); hl.y = f2bf(h.y - bf2f(hh.y));
    hh.z = f2bf(h.z); hl.z = f2bf(h.z - bf2f(hh.z));
    hh.w = f2bf(h.w); hl.w = f2bf(h.w - bf2f(hh.w));
    *(ushort4*)&Hhi[row * HID + q4] = hh;
    *(ushort4*)&Hlo[row * HID + q4] = hl;
}

// ---------------- weight conversion: fp32 -> bf16 hi/lo, padded to VTP ----------------
__global__ __launch_bounds__(256) void convw_kernel(
    const float* __restrict__ W, ushort* __restrict__ Whi, ushort* __restrict__ Wlo)
{
    size_t e0 = ((size_t)blockIdx.x * 256 + threadIdx.x) * 8;  // VTP*512/8 threads
    int row = (int)(e0 >> 9);
    uint p[4], q[4];
    if (row < VT) {
        float4 v0 = *(const float4*)&W[e0];
        float4 v1 = *(const float4*)&W[e0 + 4];
        float x[8] = {v0.x, v0.y, v0.z, v0.w, v1.x, v1.y, v1.z, v1.w};
        ushort h[8], l[8];
        #pragma unroll
        for (int j = 0; j < 8; ++j) {
            h[j] = f2bf(x[j]);
            l[j] = f2bf(x[j] - bf2f(h[j]));
        }
        #pragma unroll
        for (int j = 0; j < 4; ++j) {
            p[j] = (uint)h[2 * j] | ((uint)h[2 * j + 1] << 16);
            q[j] = (uint)l[2 * j] | ((uint)l[2 * j + 1] << 16);
        }
    } else {
        #pragma unroll
        for (int j = 0; j < 4; ++j) { p[j] = 0u; q[j] = 0u; }
    }
    *(uint4*)&Whi[e0] = make_uint4(p[0], p[1], p[2], p[3]);
    *(uint4*)&Wlo[e0] = make_uint4(q[0], q[1], q[2], q[3]);
}

__global__ __launch_bounds__(256) void convb_kernel(
    const float* __restrict__ b, float* __restrict__ bp)
{
    int i = blockIdx.x * 256 + threadIdx.x;
    if (i < VTP) bp[i] = (i < VT) ? b[i] : -1e30f;
}

// ---------------- split-bf16 MFMA projection GEMM ----------------
// C[2048, VTP] = (Ahi+Alo)(Whi+Wlo)^T + bias; fused max-pool into outmax and
// per-(tile,half) argmax partials. mode 1: store, mode 2: fmax with prev.
__global__ __launch_bounds__(256) void proj_kernel(
    const ushort* __restrict__ Ahi, const ushort* __restrict__ Alo,
    const ushort* __restrict__ Whi, const ushort* __restrict__ Wlo,
    const float* __restrict__ biasp,
    float* __restrict__ outmax,
    float* __restrict__ partval, int* __restrict__ partidx,
    int mode)
{
    __shared__ ushort As[2][4096];   // [hi/lo][128 rows x 32 k], swizzled chunks
    __shared__ ushort Bs[2][4096];

    const int t = threadIdx.x;
    const int bj0 = blockIdx.x * 128;   // col (padded vocab)
    const int bi0 = blockIdx.y * 128;   // row (batch)
    const int il = t & 15;
    const int g  = (t >> 4) & 3;
    const int wid = t >> 6;
    const int wr = wid >> 1, wc = wid & 1;

    // fragment LDS offsets (constant across k-steps)
    int aofs[4], bofs[4];
    #pragma unroll
    for (int m = 0; m < 4; ++m) {
        int r = wr * 64 + m * 16 + il;
        aofs[m] = r * 32 + (((g + (r >> 1)) & 3) << 3);
    }
    #pragma unroll
    for (int n = 0; n < 4; ++n) {
        int r = wc * 64 + n * 16 + il;
        bofs[n] = r * 32 + (((g + (r >> 1)) & 3) << 3);
    }

    f32x4 acc[4][4];
    #pragma unroll
    for (int m = 0; m < 4; ++m)
        #pragma unroll
        for (int n = 0; n < 4; ++n) acc[m][n] = 0.0f;

    for (int ks = 0; ks < 16; ++ks) {
        const int k0 = ks * 32;
        // stage 128x32 hi+lo tiles for A and B (chunk-rotated for bank spread)
        #pragma unroll
        for (int rep = 0; rep < 2; ++rep) {
            int c = t + rep * 256;
            int row = c >> 2, kc = c & 3;
            int lofs = row * 32 + (((kc + (row >> 1)) & 3) << 3);
            size_t ga = (size_t)(bi0 + row) * HID + k0 + kc * 8;
            size_t gb = (size_t)(bj0 + row) * HID + k0 + kc * 8;
            *(uint4*)&As[0][lofs] = *(const uint4*)&Ahi[ga];
            *(uint4*)&As[1][lofs] = *(const uint4*)&Alo[ga];
            *(uint4*)&Bs[0][lofs] = *(const uint4*)&Whi[gb];
            *(uint4*)&Bs[1][lofs] = *(const uint4*)&Wlo[gb];
        }
        __syncthreads();

        bf16x8 ah[4], al[4];
        #pragma unroll
        for (int m = 0; m < 4; ++m) {
            ah[m] = *(const bf16x8*)&As[0][aofs[m]];
            al[m] = *(const bf16x8*)&As[1][aofs[m]];
        }
        #pragma unroll
        for (int n = 0; n < 4; ++n) {
            bf16x8 bh = *(const bf16x8*)&Bs[0][bofs[n]];
            bf16x8 bl = *(const bf16x8*)&Bs[1][bofs[n]];
            #pragma unroll
            for (int m = 0; m < 4; ++m) {
                acc[m][n] = __builtin_amdgcn_mfma_f32_16x16x32_bf16(ah[m], bh, acc[m][n], 0, 0, 0);
                acc[m][n] = __builtin_amdgcn_mfma_f32_16x16x32_bf16(ah[m], bl, acc[m][n], 0, 0, 0);
                acc[m][n] = __builtin_amdgcn_mfma_f32_16x16x32_bf16(al[m], bh, acc[m][n], 0, 0, 0);
            }
        }
        __syncthreads();
    }

    // ---- epilogue: bias, max-pool RMW, argmax partials ----
    float bn[4]; int cn[4];
    #pragma unroll
    for (int n = 0; n < 4; ++n) {
        cn[n] = bj0 + wc * 64 + n * 16 + il;
        bn[n] = biasp[cn[n]];
    }

    #pragma unroll
    for (int m = 0; m < 4; ++m) {
        int rbase = bi0 + wr * 64 + m * 16 + g * 4;
        float bestv[4]; int besti[4];
        #pragma unroll
        for (int j = 0; j < 4; ++j) { bestv[j] = -INFINITY; besti[j] = 0x7fffffff; }

        #pragma unroll
        for (int n = 0; n < 4; ++n) {
            f32x4 v = acc[m][n];
            #pragma unroll
            for (int j = 0; j < 4; ++j) {
                float logit = v[j] + bn[n];
                int row = rbase + j;
                if (cn[n] < VT) {
                    float* op = &outmax[(size_t)row * VT + cn[n]];
                    float o = logit;
                    if (mode == 2) o = fmaxf(o, *op);
                    *op = o;
                }
                if (logit > bestv[j]) { bestv[j] = logit; besti[j] = cn[n]; }
            }
        }
        #pragma unroll
        for (int j = 0; j < 4; ++j) {
            float bv = bestv[j]; int bi = besti[j];
            #pragma unroll
            for (int off = 1; off < 16; off <<= 1) {
                float ov = __shfl_xor(bv, off, 64);
                int   oi = __shfl_xor(bi, off, 64);
                if (ov > bv || (ov == bv && oi < bi)) { bv = ov; bi = oi; }
            }
            if (il == 0) {
                partval[(size_t)(rbase + j) * PSTRIDE + blockIdx.x * 2 + wc] = bv;
                partidx[(size_t)(rbase + j) * PSTRIDE + blockIdx.x * 2 + wc] = bi;
            }
        }
    }
}

// ---------------- fp32 GEMM for LSTM gates: C = A0*B0^T + A1*B1^T + b ----------------
__global__ __launch_bounds__(256) void gemm_kernel(
    const float* __restrict__ A0, const float* __restrict__ B0, int K0,
    const float* __restrict__ A1, const float* __restrict__ B1, int K1,
    const float* __restrict__ bias0, const float* __restrict__ bias1,
    int N, float* __restrict__ Cout)
{
    __shared__ float As[32 * 68];
    __shared__ float Bs[32 * 68];
    const int bj0 = blockIdx.x * 64;
    const int bi0 = blockIdx.y * 64;
    const int t = threadIdx.x;
    const int tr = t >> 4, tc = t & 15;

    float acc[4][4] = {};

    const float* Aseg[2] = {A0, A1};
    const float* Bseg[2] = {B0, B1};
    const int    Kseg[2] = {K0, K1};

    for (int s = 0; s < 2; ++s) {
        const float* __restrict__ A  = Aseg[s];
        const float* __restrict__ Bw = Bseg[s];
        const int K = Kseg[s];
        for (int ch = 0; ch < K; ch += 32) {
            #pragma unroll
            for (int rep = 0; rep < 2; ++rep) {
                int li = t + rep * 256;
                int row = li >> 3, k4 = (li & 7) << 2;
                float4 va = *(const float4*)&A[(size_t)(bi0 + row) * K + ch + k4];
                float4 vb = *(const float4*)&Bw[(size_t)(bj0 + row) * K + ch + k4];
                As[(k4 + 0) * 68 + row] = va.x; As[(k4 + 1) * 68 + row] = va.y;
                As[(k4 + 2) * 68 + row] = va.z; As[(k4 + 3) * 68 + row] = va.w;
                Bs[(k4 + 0) * 68 + row] = vb.x; Bs[(k4 + 1) * 68 + row] = vb.y;
                Bs[(k4 + 2) * 68 + row] = vb.z; Bs[(k4 + 3) * 68 + row] = vb.w;
            }
            __syncthreads();
            #pragma unroll
            for (int k = 0; k < 32; ++k) {
                float4 a = *(const float4*)&As[k * 68 + tr * 4];
                float4 b = *(const float4*)&Bs[k * 68 + tc * 4];
                acc[0][0] += a.x * b.x; acc[0][1] += a.x * b.y; acc[0][2] += a.x * b.z; acc[0][3] += a.x * b.w;
                acc[1][0] += a.y * b.x; acc[1][1] += a.y * b.y; acc[1][2] += a.y * b.z; acc[1][3] += a.y * b.w;
                acc[2][0] += a.z * b.x; acc[2][1] += a.z * b.y; acc[2][2] += a.z * b.z; acc[2][3] += a.z * b.w;
                acc[3][0] += a.w * b.x; acc[3][1] += a.w * b.y; acc[3][2] += a.w * b.z; acc[3][3] += a.w * b.w;
            }
            __syncthreads();
        }
    }

    #pragma unroll
    for (int i = 0; i < 4; ++i) {
        int row = bi0 + tr * 4 + i;
        float4 v;
        int col = bj0 + tc * 4;
        v.x = acc[i][0] + bias0[col + 0] + bias1[col + 0];
        v.y = acc[i][1] + bias0[col + 1] + bias1[col + 1];
        v.z = acc[i][2] + bias0[col + 2] + bias1[col + 2];
        v.w = acc[i][3] + bias0[col + 3] + bias1[col + 3];
        *(float4*)&Cout[(size_t)row * N + col] = v;
    }
}

// ---------------- argmax finalize: reduce NPART partials per row ----------------
__global__ __launch_bounds__(128) void finalize_kernel(
    const float* __restrict__ partval, const int* __restrict__ partidx,
    int* __restrict__ tok)
{
    __shared__ float sv[128];
    __shared__ int   si[128];
    int row = blockIdx.x, t = threadIdx.x;
    float v = -INFINITY; int ix = 0x7fffffff;
    if (t < NPART) { v = partval[(size_t)row * PSTRIDE + t]; ix = partidx[(size_t)row * PSTRIDE + t]; }
    sv[t] = v; si[t] = ix;
    __syncthreads();
    for (int s = 64; s > 0; s >>= 1) {
        if (t < s) {
            float ov = sv[t + s]; int oi = si[t + s];
            if (ov > sv[t] || (ov == sv[t] && oi < si[t])) { sv[t] = ov; si[t] = oi; }
        }
        __syncthreads();
    }
    if (t == 0) tok[row] = si[0];
}

extern "C" void kernel_launch(void* const* d_in, const int* in_sizes, int n_in,
                              void* d_out, int out_size, void* d_ws, size_t ws_size,
                              hipStream_t stream) {
    const int*   src       = (const int*)d_in[0];
    const float* src_embed = (const float*)d_in[1];
    const float* tgt_embed = (const float*)d_in[2];
    const float* enc_Wih   = (const float*)d_in[3];
    const float* enc_Whh   = (const float*)d_in[4];
    const float* enc_bih   = (const float*)d_in[5];
    const float* enc_bhh   = (const float*)d_in[6];
    const float* dec_Wih   = (const float*)d_in[7];
    const float* dec_Whh   = (const float*)d_in[8];
    const float* dec_bih   = (const float*)d_in[9];
    const float* dec_bhh   = (const float*)d_in[10];
    const float* proj_W    = (const float*)d_in[11];
    const float* proj_b    = (const float*)d_in[12];
    float* out = (float*)d_out;

    char* ws = (char*)d_ws;
    float* X     = (float*)ws;                 ws += (size_t)BB * EMB * 4;       // 1 MB
    float* H     = (float*)ws;                 ws += (size_t)BB * HID * 4;       // 4 MB
    float* C     = (float*)ws;                 ws += (size_t)BB * HID * 4;       // 4 MB
    float* GATES = (float*)ws;                 ws += (size_t)BB * G4 * 4;        // 16 MB
    float* PV    = (float*)ws;                 ws += (size_t)BB * PSTRIDE * 4;   // 1 MB
    int*   PI    = (int*)ws;                   ws += (size_t)BB * PSTRIDE * 4;   // 1 MB
    int*   TOK   = (int*)ws;                   ws += (size_t)BB * 4;
    ushort* Hhi  = (ushort*)ws;                ws += (size_t)BB * HID * 2;       // 2 MB
    ushort* Hlo  = (ushort*)ws;                ws += (size_t)BB * HID * 2;       // 2 MB
    ushort* Whi  = (ushort*)ws;                ws += (size_t)VTP * HID * 2;      // 8.26 MB
    ushort* Wlo  = (ushort*)ws;                ws += (size_t)VTP * HID * 2;      // 8.26 MB
    float* biasp = (float*)ws;                 ws += (size_t)VTP * 4;

    hipMemsetAsync(H, 0, (size_t)BB * HID * 4, stream);
    hipMemsetAsync(C, 0, (size_t)BB * HID * 4, stream);
    hipMemsetAsync(TOK, 0, (size_t)BB * 4, stream);   // BOS = 0

    // weight conversion for projection
    convw_kernel<<<VTP * HID / 8 / 256, 256, 0, stream>>>(proj_W, Whi, Wlo);
    convb_kernel<<<(VTP + 255) / 256, 256, 0, stream>>>(proj_b, biasp);

    dim3 ggate(G4 / 64, BB / 64);   // 32 x 32
    dim3 gproj(NTILE, BB / 128);    // 63 x 16

    // ---- encoder: 2 steps ----
    for (int tstep = 0; tstep < 2; ++tstep) {
        gather_kernel<<<256, 256, 0, stream>>>(X, src_embed, src, 2, tstep);
        gemm_kernel<<<ggate, 256, 0, stream>>>(X, enc_Wih, EMB, H, enc_Whh, HID,
            enc_bih, enc_bhh, G4, GATES);
        cell_kernel<<<1024, 256, 0, stream>>>(GATES, C, H, Hhi, Hlo);
    }

    // ---- decoder: 9 greedy steps ----
    for (int s = 0; s < NSTEP; ++s) {
        gather_kernel<<<256, 256, 0, stream>>>(X, tgt_embed, TOK, 1, 0);
        gemm_kernel<<<ggate, 256, 0, stream>>>(X, dec_Wih, EMB, H, dec_Whh, HID,
            dec_bih, dec_bhh, G4, GATES);
        cell_kernel<<<1024, 256, 0, stream>>>(GATES, C, H, Hhi, Hlo);
        proj_kernel<<<gproj, 256, 0, stream>>>(Hhi, Hlo, Whi, Wlo, biasp,
            out, PV, PI, (s == 0 ? 1 : 2));
        if (s + 1 < NSTEP)
            finalize_kernel<<<BB, 128, 0, stream>>>(PV, PI, TOK);
    }
}

// Round 3
// 1207.519 us; speedup vs baseline: 2.7556x; 1.7262x over previous
//
#include <hip/hip_runtime.h>
#include <math.h>

#define BB 2048
#define EMB 128
#define HID 512
#define G4 2048    // 4*HID
#define VT 8000
#define VTP2 8192  // padded to 64*128
#define NSTEP 9
#define NTILE2 64  // col tiles of 128

typedef short bf16x8 __attribute__((ext_vector_type(8)));
typedef float f32x4 __attribute__((ext_vector_type(4)));

__device__ __forceinline__ ushort f2bf(float x) {
    uint u = __float_as_uint(x);
    uint r = (u + 0x7fffu + ((u >> 16) & 1u)) >> 16;
    return (ushort)r;
}
__device__ __forceinline__ float bf2f(ushort h) {
    return __uint_as_float(((uint)h) << 16);
}

// ---------------- embedding gather -> bf16 hi/lo ----------------
__global__ __launch_bounds__(256) void gather_kernel(
    ushort* __restrict__ Xhi, ushort* __restrict__ Xlo,
    const float* __restrict__ table,
    const int* __restrict__ idx, int stride, int offset)
{
    int t = blockIdx.x * 256 + threadIdx.x;   // BB*32 threads
    int row = t >> 5, c4 = (t & 31) << 2;
    int tok = idx[row * stride + offset];
    float4 v = *(const float4*)&table[tok * EMB + c4];
    ushort4 hh, hl;
    hh.x = f2bf(v.x); hl.x = f2bf(v.x - bf2f(hh.x));
    hh.y = f2bf(v.y); hl.y = f2bf(v.y - bf2f(hh.y));
    hh.z = f2bf(v.z); hl.z = f2bf(v.z - bf2f(hh.z));
    hh.w = f2bf(v.w); hl.w = f2bf(v.w - bf2f(hh.w));
    *(ushort4*)&Xhi[row * EMB + c4] = hh;
    *(ushort4*)&Xlo[row * EMB + c4] = hl;
}

// ---------------- LSTM cell elementwise (C fp32; H emitted as bf16 hi/lo) ----------------
__device__ __forceinline__ float sigm(float x) { return 1.0f / (1.0f + expf(-x)); }

__global__ __launch_bounds__(256) void cell_kernel(
    const float* __restrict__ gates, float* __restrict__ C,
    ushort* __restrict__ Hhi, ushort* __restrict__ Hlo)
{
    int t = blockIdx.x * 256 + threadIdx.x;   // BB*HID/4 threads
    int row = t >> 7, q4 = (t & 127) << 2;
    const float4 gi = *(const float4*)&gates[row * G4 + q4];
    const float4 gf = *(const float4*)&gates[row * G4 + 512 + q4];
    const float4 gg = *(const float4*)&gates[row * G4 + 1024 + q4];
    const float4 go = *(const float4*)&gates[row * G4 + 1536 + q4];
    float4 c = *(const float4*)&C[row * HID + q4];
    float4 h;
    float ci, cf, cg, co;

    ci = sigm(gi.x); cf = sigm(gf.x); cg = tanhf(gg.x); co = sigm(go.x);
    c.x = cf * c.x + ci * cg;  h.x = co * tanhf(c.x);
    ci = sigm(gi.y); cf = sigm(gf.y); cg = tanhf(gg.y); co = sigm(go.y);
    c.y = cf * c.y + ci * cg;  h.y = co * tanhf(c.y);
    ci = sigm(gi.z); cf = sigm(gf.z); cg = tanhf(gg.z); co = sigm(go.z);
    c.z = cf * c.z + ci * cg;  h.z = co * tanhf(c.z);
    ci = sigm(gi.w); cf = sigm(gf.w); cg = tanhf(gg.w); co = sigm(go.w);
    c.w = cf * c.w + ci * cg;  h.w = co * tanhf(c.w);

    *(float4*)&C[row * HID + q4] = c;

    ushort4 hh, hl;
    hh.x = f2bf(h.x); hl.x = f2bf(h.x - bf2f(hh.x));
    hh.y = f2bf(h.y); hl.y = f2bf(h.y - bf2f(hh.y));
    hh.z = f2bf(h.z); hl.z = f2bf(h.z - bf2f(hh.z));
    hh.w = f2bf(h.w); hl.w = f2bf(h.w - bf2f(hh.w));
    *(ushort4*)&Hhi[row * HID + q4] = hh;
    *(ushort4*)&Hlo[row * HID + q4] = hl;
}

// ---------------- weight conversion: fp32 -> bf16 hi/lo (exact size, mult of 8) ----------------
__global__ __launch_bounds__(256) void convpair_kernel(
    const float* __restrict__ W, ushort* __restrict__ Whi, ushort* __restrict__ Wlo)
{
    size_t e0 = ((size_t)blockIdx.x * 256 + threadIdx.x) * 8;
    float4 v0 = *(const float4*)&W[e0];
    float4 v1 = *(const float4*)&W[e0 + 4];
    float x[8] = {v0.x, v0.y, v0.z, v0.w, v1.x, v1.y, v1.z, v1.w};
    uint p[4], q[4];
    #pragma unroll
    for (int j = 0; j < 4; ++j) {
        ushort h0 = f2bf(x[2 * j]),     l0 = f2bf(x[2 * j] - bf2f(h0));
        ushort h1 = f2bf(x[2 * j + 1]), l1 = f2bf(x[2 * j + 1] - bf2f(h1));
        p[j] = (uint)h0 | ((uint)h1 << 16);
        q[j] = (uint)l0 | ((uint)l1 << 16);
    }
    *(uint4*)&Whi[e0] = make_uint4(p[0], p[1], p[2], p[3]);
    *(uint4*)&Wlo[e0] = make_uint4(q[0], q[1], q[2], q[3]);
}

// proj weight: padded to VTP2 rows (zeros)
__global__ __launch_bounds__(256) void convw_kernel(
    const float* __restrict__ W, ushort* __restrict__ Whi, ushort* __restrict__ Wlo)
{
    size_t e0 = ((size_t)blockIdx.x * 256 + threadIdx.x) * 8;  // VTP2*HID/8 threads
    int row = (int)(e0 >> 9);
    uint p[4], q[4];
    if (row < VT) {
        float4 v0 = *(const float4*)&W[e0];
        float4 v1 = *(const float4*)&W[e0 + 4];
        float x[8] = {v0.x, v0.y, v0.z, v0.w, v1.x, v1.y, v1.z, v1.w};
        #pragma unroll
        for (int j = 0; j < 4; ++j) {
            ushort h0 = f2bf(x[2 * j]),     l0 = f2bf(x[2 * j] - bf2f(h0));
            ushort h1 = f2bf(x[2 * j + 1]), l1 = f2bf(x[2 * j + 1] - bf2f(h1));
            p[j] = (uint)h0 | ((uint)h1 << 16);
            q[j] = (uint)l0 | ((uint)l1 << 16);
        }
    } else {
        #pragma unroll
        for (int j = 0; j < 4; ++j) { p[j] = 0u; q[j] = 0u; }
    }
    *(uint4*)&Whi[e0] = make_uint4(p[0], p[1], p[2], p[3]);
    *(uint4*)&Wlo[e0] = make_uint4(q[0], q[1], q[2], q[3]);
}

__global__ __launch_bounds__(256) void convb_kernel(
    const float* __restrict__ b, float* __restrict__ bp)
{
    int i = blockIdx.x * 256 + threadIdx.x;
    if (i < VTP2) bp[i] = (i < VT) ? b[i] : -1e30f;
}

__global__ __launch_bounds__(256) void bsum_kernel(
    const float* __restrict__ b0, const float* __restrict__ b1, float* __restrict__ bs)
{
    int i = blockIdx.x * 256 + threadIdx.x;
    if (i < G4) bs[i] = b0[i] + b1[i];
}

// ---------------- split-bf16 MFMA gates GEMM ----------------
// GATES[2048, 2048] = X*Wih^T + H*Whh^T + bsum (split-bf16, 3-term)
__global__ __launch_bounds__(256) void gates_kernel(
    const ushort* __restrict__ Xhi, const ushort* __restrict__ Xlo,
    const ushort* __restrict__ Hhi, const ushort* __restrict__ Hlo,
    const ushort* __restrict__ WihH, const ushort* __restrict__ WihL,
    const ushort* __restrict__ WhhH, const ushort* __restrict__ WhhL,
    const float* __restrict__ bsum, float* __restrict__ Cout)
{
    __shared__ char smem[32768];
    ushort* As = (ushort*)smem;          // [2][4096]
    ushort* Bs = As + 8192;              // [2][4096]

    const int t = threadIdx.x;
    const int n = blockIdx.x;            // 256 blocks
    const int tile = (n & 7) * 2 + ((n >> 3) & 1);
    const int rb = n >> 4;
    const int bj0 = tile * 128;
    const int bi0 = rb * 128;
    const int il = t & 15;
    const int g  = (t >> 4) & 3;
    const int wid = t >> 6;
    const int wr = wid >> 1, wc = wid & 1;

    int aofs[4], bofs[4];
    #pragma unroll
    for (int m = 0; m < 4; ++m) {
        int r = wr * 64 + m * 16 + il;
        aofs[m] = r * 32 + (((g + (r >> 1)) & 3) << 3);
    }
    #pragma unroll
    for (int nn = 0; nn < 4; ++nn) {
        int r = wc * 64 + nn * 16 + il;
        bofs[nn] = r * 32 + (((g + (r >> 1)) & 3) << 3);
    }

    f32x4 acc[4][4];
    #pragma unroll
    for (int m = 0; m < 4; ++m)
        #pragma unroll
        for (int nn = 0; nn < 4; ++nn) acc[m][nn] = 0.0f;

    for (int ks = 0; ks < 20; ++ks) {
        const ushort *Ah, *Al, *Bh, *Bl;
        int K, k0;
        if (ks < 4) { Ah = Xhi; Al = Xlo; Bh = WihH; Bl = WihL; K = EMB; k0 = ks * 32; }
        else        { Ah = Hhi; Al = Hlo; Bh = WhhH; Bl = WhhL; K = HID; k0 = (ks - 4) * 32; }
        #pragma unroll
        for (int rep = 0; rep < 2; ++rep) {
            int c = t + rep * 256;
            int row = c >> 2, kc = c & 3;
            int lofs = row * 32 + (((kc + (row >> 1)) & 3) << 3);
            size_t ga = (size_t)(bi0 + row) * K + k0 + kc * 8;
            size_t gb = (size_t)(bj0 + row) * K + k0 + kc * 8;
            *(uint4*)&As[lofs]        = *(const uint4*)&Ah[ga];
            *(uint4*)&As[4096 + lofs] = *(const uint4*)&Al[ga];
            *(uint4*)&Bs[lofs]        = *(const uint4*)&Bh[gb];
            *(uint4*)&Bs[4096 + lofs] = *(const uint4*)&Bl[gb];
        }
        __syncthreads();

        bf16x8 ah[4], al[4];
        #pragma unroll
        for (int m = 0; m < 4; ++m) {
            ah[m] = *(const bf16x8*)&As[aofs[m]];
            al[m] = *(const bf16x8*)&As[4096 + aofs[m]];
        }
        #pragma unroll
        for (int nn = 0; nn < 4; ++nn) {
            bf16x8 bh = *(const bf16x8*)&Bs[bofs[nn]];
            bf16x8 bl = *(const bf16x8*)&Bs[4096 + bofs[nn]];
            #pragma unroll
            for (int m = 0; m < 4; ++m) {
                acc[m][nn] = __builtin_amdgcn_mfma_f32_16x16x32_bf16(ah[m], bh, acc[m][nn], 0, 0, 0);
                acc[m][nn] = __builtin_amdgcn_mfma_f32_16x16x32_bf16(ah[m], bl, acc[m][nn], 0, 0, 0);
                acc[m][nn] = __builtin_amdgcn_mfma_f32_16x16x32_bf16(al[m], bh, acc[m][nn], 0, 0, 0);
            }
        }
        __syncthreads();
    }

    // ---- epilogue: bias, LDS transpose, coalesced float4 stores ----
    float* Tr = (float*)smem;   // [32][132]
    float bn[4];
    #pragma unroll
    for (int nn = 0; nn < 4; ++nn) bn[nn] = bsum[bj0 + wc * 64 + nn * 16 + il];

    #pragma unroll
    for (int m = 0; m < 4; ++m) {
        #pragma unroll
        for (int nn = 0; nn < 4; ++nn)
            #pragma unroll
            for (int j = 0; j < 4; ++j)
                Tr[(wr * 16 + g * 4 + j) * 132 + wc * 64 + nn * 16 + il] = acc[m][nn][j] + bn[nn];
        __syncthreads();
        #pragma unroll
        for (int it = 0; it < 4; ++it) {
            int lr2 = it * 8 + (t >> 5);
            int c0 = (t & 31) * 4;
            int row = bi0 + m * 16 + ((lr2 >> 4) << 6) + (lr2 & 15);
            float4 v = *(float4*)&Tr[lr2 * 132 + c0];
            *(float4*)&Cout[(size_t)row * G4 + bj0 + c0] = v;
        }
        __syncthreads();
    }
}

// ---------------- split-bf16 MFMA projection GEMM ----------------
// logits[2048, VTP2] = H·Wp^T + bias; fused max-pool RMW into outmax and
// per-tile argmax partials. mode 1: store, mode 2: fmax with prev.
__global__ __launch_bounds__(256) void proj_kernel(
    const ushort* __restrict__ Ahi, const ushort* __restrict__ Alo,
    const ushort* __restrict__ Whi, const ushort* __restrict__ Wlo,
    const float* __restrict__ biasp,
    float* __restrict__ outmax,
    float* __restrict__ partval, int* __restrict__ partidx,
    int mode)
{
    __shared__ char smem[32768];
    ushort* As = (ushort*)smem;          // [2][4096]
    ushort* Bs = As + 8192;              // [2][4096]

    const int t = threadIdx.x;
    const int n = blockIdx.x;            // 1024 blocks
    const int xcd = n & 7;
    const int j8 = n >> 3;               // 0..127
    const int tile = xcd * 8 + (j8 & 7);
    const int rb = j8 >> 3;              // 0..15
    const int bj0 = tile * 128;
    const int bi0 = rb * 128;
    const int il = t & 15;
    const int g  = (t >> 4) & 3;
    const int wid = t >> 6;
    const int wr = wid >> 1, wc = wid & 1;

    int aofs[4], bofs[4];
    #pragma unroll
    for (int m = 0; m < 4; ++m) {
        int r = wr * 64 + m * 16 + il;
        aofs[m] = r * 32 + (((g + (r >> 1)) & 3) << 3);
    }
    #pragma unroll
    for (int nn = 0; nn < 4; ++nn) {
        int r = wc * 64 + nn * 16 + il;
        bofs[nn] = r * 32 + (((g + (r >> 1)) & 3) << 3);
    }

    f32x4 acc[4][4];
    #pragma unroll
    for (int m = 0; m < 4; ++m)
        #pragma unroll
        for (int nn = 0; nn < 4; ++nn) acc[m][nn] = 0.0f;

    for (int ks = 0; ks < 16; ++ks) {
        const int k0 = ks * 32;
        #pragma unroll
        for (int rep = 0; rep < 2; ++rep) {
            int c = t + rep * 256;
            int row = c >> 2, kc = c & 3;
            int lofs = row * 32 + (((kc + (row >> 1)) & 3) << 3);
            size_t ga = (size_t)(bi0 + row) * HID + k0 + kc * 8;
            size_t gb = (size_t)(bj0 + row) * HID + k0 + kc * 8;
            *(uint4*)&As[lofs]        = *(const uint4*)&Ahi[ga];
            *(uint4*)&As[4096 + lofs] = *(const uint4*)&Alo[ga];
            *(uint4*)&Bs[lofs]        = *(const uint4*)&Whi[gb];
            *(uint4*)&Bs[4096 + lofs] = *(const uint4*)&Wlo[gb];
        }
        __syncthreads();

        bf16x8 ah[4], al[4];
        #pragma unroll
        for (int m = 0; m < 4; ++m) {
            ah[m] = *(const bf16x8*)&As[aofs[m]];
            al[m] = *(const bf16x8*)&As[4096 + aofs[m]];
        }
        #pragma unroll
        for (int nn = 0; nn < 4; ++nn) {
            bf16x8 bh = *(const bf16x8*)&Bs[bofs[nn]];
            bf16x8 bl = *(const bf16x8*)&Bs[4096 + bofs[nn]];
            #pragma unroll
            for (int m = 0; m < 4; ++m) {
                acc[m][nn] = __builtin_amdgcn_mfma_f32_16x16x32_bf16(ah[m], bh, acc[m][nn], 0, 0, 0);
                acc[m][nn] = __builtin_amdgcn_mfma_f32_16x16x32_bf16(ah[m], bl, acc[m][nn], 0, 0, 0);
                acc[m][nn] = __builtin_amdgcn_mfma_f32_16x16x32_bf16(al[m], bh, acc[m][nn], 0, 0, 0);
            }
        }
        __syncthreads();
    }

    // ---- epilogue: bias, LDS transpose, coalesced float4 RMW + argmax ----
    float* Tr = (float*)smem;   // [32][132]
    float bn[4];
    #pragma unroll
    for (int nn = 0; nn < 4; ++nn) bn[nn] = biasp[bj0 + wc * 64 + nn * 16 + il];

    #pragma unroll
    for (int m = 0; m < 4; ++m) {
        #pragma unroll
        for (int nn = 0; nn < 4; ++nn)
            #pragma unroll
            for (int j = 0; j < 4; ++j)
                Tr[(wr * 16 + g * 4 + j) * 132 + wc * 64 + nn * 16 + il] = acc[m][nn][j] + bn[nn];
        __syncthreads();
        #pragma unroll
        for (int it = 0; it < 4; ++it) {
            int lr2 = it * 8 + (t >> 5);
            int c0 = (t & 31) * 4;
            int row = bi0 + m * 16 + ((lr2 >> 4) << 6) + (lr2 & 15);
            int col = bj0 + c0;
            float4 cur = *(float4*)&Tr[lr2 * 132 + c0];

            // thread-local argmax over 4 ascending cols (padded cols carry -1e30 bias)
            float bv = cur.x; int bix = col;
            if (cur.y > bv) { bv = cur.y; bix = col + 1; }
            if (cur.z > bv) { bv = cur.z; bix = col + 2; }
            if (cur.w > bv) { bv = cur.w; bix = col + 3; }
            #pragma unroll
            for (int off = 1; off < 32; off <<= 1) {
                float ov = __shfl_xor(bv, off, 64);
                int   oi = __shfl_xor(bix, off, 64);
                if (ov > bv || (ov == bv && oi < bix)) { bv = ov; bix = oi; }
            }
            if ((t & 31) == 0) {
                partval[(size_t)row * NTILE2 + tile] = bv;
                partidx[(size_t)row * NTILE2 + tile] = bix;
            }

            if (col < VT) {
                float* op = &outmax[(size_t)row * VT + col];
                float4 o = cur;
                if (mode == 2) {
                    float4 p = *(const float4*)op;
                    o.x = fmaxf(o.x, p.x); o.y = fmaxf(o.y, p.y);
                    o.z = fmaxf(o.z, p.z); o.w = fmaxf(o.w, p.w);
                }
                *(float4*)op = o;
            }
        }
        __syncthreads();
    }
}

// ---------------- argmax finalize: reduce 64 partials per row ----------------
__global__ __launch_bounds__(64) void finalize_kernel(
    const float* __restrict__ partval, const int* __restrict__ partidx,
    int* __restrict__ tok)
{
    int row = blockIdx.x, t = threadIdx.x;
    float v = partval[(size_t)row * NTILE2 + t];
    int  ix = partidx[(size_t)row * NTILE2 + t];
    #pragma unroll
    for (int off = 1; off < 64; off <<= 1) {
        float ov = __shfl_xor(v, off, 64);
        int   oi = __shfl_xor(ix, off, 64);
        if (ov > v || (ov == v && oi < ix)) { v = ov; ix = oi; }
    }
    if (t == 0) tok[row] = ix;
}

extern "C" void kernel_launch(void* const* d_in, const int* in_sizes, int n_in,
                              void* d_out, int out_size, void* d_ws, size_t ws_size,
                              hipStream_t stream) {
    const int*   src       = (const int*)d_in[0];
    const float* src_embed = (const float*)d_in[1];
    const float* tgt_embed = (const float*)d_in[2];
    const float* enc_Wih   = (const float*)d_in[3];
    const float* enc_Whh   = (const float*)d_in[4];
    const float* enc_bih   = (const float*)d_in[5];
    const float* enc_bhh   = (const float*)d_in[6];
    const float* dec_Wih   = (const float*)d_in[7];
    const float* dec_Whh   = (const float*)d_in[8];
    const float* dec_bih   = (const float*)d_in[9];
    const float* dec_bhh   = (const float*)d_in[10];
    const float* proj_W    = (const float*)d_in[11];
    const float* proj_b    = (const float*)d_in[12];
    float* out = (float*)d_out;

    char* ws = (char*)d_ws;
    float*  C     = (float*)ws;   ws += (size_t)BB * HID * 4;        // 4 MB
    float*  GATES = (float*)ws;   ws += (size_t)BB * G4 * 4;         // 16 MB
    float*  PV    = (float*)ws;   ws += (size_t)BB * NTILE2 * 4;     // 512 KB
    int*    PI    = (int*)ws;     ws += (size_t)BB * NTILE2 * 4;     // 512 KB
    int*    TOK   = (int*)ws;     ws += (size_t)BB * 4;              // 8 KB
    ushort* Xhi   = (ushort*)ws;  ws += (size_t)BB * EMB * 2;
    ushort* Xlo   = (ushort*)ws;  ws += (size_t)BB * EMB * 2;
    ushort* Hhi   = (ushort*)ws;  ws += (size_t)BB * HID * 2;
    ushort* Hlo   = (ushort*)ws;  ws += (size_t)BB * HID * 2;
    ushort* PWhi  = (ushort*)ws;  ws += (size_t)VTP2 * HID * 2;      // 8 MB
    ushort* PWlo  = (ushort*)ws;  ws += (size_t)VTP2 * HID * 2;      // 8 MB
    float*  biasp = (float*)ws;   ws += (size_t)VTP2 * 4;
    ushort* eWihH = (ushort*)ws;  ws += (size_t)G4 * EMB * 2;
    ushort* eWihL = (ushort*)ws;  ws += (size_t)G4 * EMB * 2;
    ushort* eWhhH = (ushort*)ws;  ws += (size_t)G4 * HID * 2;
    ushort* eWhhL = (ushort*)ws;  ws += (size_t)G4 * HID * 2;
    ushort* dWihH = (ushort*)ws;  ws += (size_t)G4 * EMB * 2;
    ushort* dWihL = (ushort*)ws;  ws += (size_t)G4 * EMB * 2;
    ushort* dWhhH = (ushort*)ws;  ws += (size_t)G4 * HID * 2;
    ushort* dWhhL = (ushort*)ws;  ws += (size_t)G4 * HID * 2;
    float*  BSe   = (float*)ws;   ws += (size_t)G4 * 4;
    float*  BSd   = (float*)ws;   ws += (size_t)G4 * 4;

    hipMemsetAsync(C, 0, (size_t)BB * HID * 4, stream);
    hipMemsetAsync(Hhi, 0, (size_t)BB * HID * 2, stream);
    hipMemsetAsync(Hlo, 0, (size_t)BB * HID * 2, stream);
    hipMemsetAsync(TOK, 0, (size_t)BB * 4, stream);   // BOS = 0

    // weight conversions
    convw_kernel<<<VTP2 * HID / 8 / 256, 256, 0, stream>>>(proj_W, PWhi, PWlo);
    convb_kernel<<<VTP2 / 256, 256, 0, stream>>>(proj_b, biasp);
    convpair_kernel<<<G4 * EMB / 8 / 256, 256, 0, stream>>>(enc_Wih, eWihH, eWihL);
    convpair_kernel<<<G4 * HID / 8 / 256, 256, 0, stream>>>(enc_Whh, eWhhH, eWhhL);
    convpair_kernel<<<G4 * EMB / 8 / 256, 256, 0, stream>>>(dec_Wih, dWihH, dWihL);
    convpair_kernel<<<G4 * HID / 8 / 256, 256, 0, stream>>>(dec_Whh, dWhhH, dWhhL);
    bsum_kernel<<<G4 / 256, 256, 0, stream>>>(enc_bih, enc_bhh, BSe);
    bsum_kernel<<<G4 / 256, 256, 0, stream>>>(dec_bih, dec_bhh, BSd);

    // ---- encoder: 2 steps ----
    for (int tstep = 0; tstep < 2; ++tstep) {
        gather_kernel<<<256, 256, 0, stream>>>(Xhi, Xlo, src_embed, src, 2, tstep);
        gates_kernel<<<256, 256, 0, stream>>>(Xhi, Xlo, Hhi, Hlo,
            eWihH, eWihL, eWhhH, eWhhL, BSe, GATES);
        cell_kernel<<<1024, 256, 0, stream>>>(GATES, C, Hhi, Hlo);
    }

    // ---- decoder: 9 greedy steps ----
    for (int s = 0; s < NSTEP; ++s) {
        gather_kernel<<<256, 256, 0, stream>>>(Xhi, Xlo, tgt_embed, TOK, 1, 0);
        gates_kernel<<<256, 256, 0, stream>>>(Xhi, Xlo, Hhi, Hlo,
            dWihH, dWihL, dWhhH, dWhhL, BSd, GATES);
        cell_kernel<<<1024, 256, 0, stream>>>(GATES, C, Hhi, Hlo);
        proj_kernel<<<1024, 256, 0, stream>>>(Hhi, Hlo, PWhi, PWlo, biasp,
            out, PV, PI, (s == 0 ? 1 : 2));
        if (s + 1 < NSTEP)
            finalize_kernel<<<BB, 64, 0, stream>>>(PV, PI, TOK);
    }
}

// Round 4
// 1119.713 us; speedup vs baseline: 2.9716x; 1.0784x over previous
//
#include <hip/hip_runtime.h>
#include <math.h>

#define BB 2048
#define EMB 128
#define HID 512
#define G4 2048    // 4*HID
#define VT 8000
#define VTP2 8192  // padded to 64*128
#define NSTEP 9
#define NTILE2 64  // proj col tiles of 128

typedef short bf16x8 __attribute__((ext_vector_type(8)));
typedef float f32x4 __attribute__((ext_vector_type(4)));

__device__ __forceinline__ ushort f2bf(float x) {
    uint u = __float_as_uint(x);
    uint r = (u + 0x7fffu + ((u >> 16) & 1u)) >> 16;
    return (ushort)r;
}
__device__ __forceinline__ float bf2f(ushort h) {
    return __uint_as_float(((uint)h) << 16);
}
__device__ __forceinline__ float sigm(float x) { return 1.0f / (1.0f + expf(-x)); }

// async global->LDS, 16B per lane, LDS dest = wave-uniform base + lane*16
__device__ __forceinline__ void gload16(const ushort* g, ushort* l) {
    __builtin_amdgcn_global_load_lds(
        (const __attribute__((address_space(1))) uint*)g,
        (__attribute__((address_space(3))) uint*)l, 16, 0, 0);
}

// Stage a 128x32 hi/lo A,B tile set (32 KB) into Sb.
// Wave roles: wid 0=A_hi 1=A_lo 2=B_hi 3=B_lo; each wave 8 chunks of 1 KB.
// Global source pre-swizzled so LDS content matches the rotated-chunk layout:
// LDS slot (row, kc') holds element (row, (kc' - (row>>1)) & 3).
__device__ __forceinline__ void stage_tile(
    ushort* Sb,
    const ushort* __restrict__ Ah, const ushort* __restrict__ Al,
    const ushort* __restrict__ Bh, const ushort* __restrict__ Bl,
    int biA, int biB, int K, int k0, int wid, int lane)
{
    const ushort* src = (wid < 2) ? ((wid == 0) ? Ah : Al)
                                  : ((wid == 2) ? Bh : Bl);
    const int rowbase = (wid < 2) ? biA : biB;
    const int rl = lane >> 2, kcp = lane & 3;
    #pragma unroll
    for (int j = 0; j < 8; ++j) {
        int row = j * 16 + rl;
        int kc = (kcp - (row >> 1)) & 3;
        const ushort* g = src + (size_t)(rowbase + row) * K + k0 + kc * 8;
        gload16(g, Sb + wid * 4096 + j * 512);
    }
}

// ---------------- fused gather: (finalize-argmax | src | BOS) -> embed -> hi/lo ----------------
// mode 0: tok = src[row*2+offset]; mode 1: tok = 0 (BOS); mode 2: argmax-reduce partials.
__global__ __launch_bounds__(64) void gather2_kernel(
    ushort* __restrict__ Xhi, ushort* __restrict__ Xlo,
    const float* __restrict__ table,
    const int* __restrict__ src, int mode, int offset,
    const float* __restrict__ partval, const int* __restrict__ partidx)
{
    int row = blockIdx.x, t = threadIdx.x;
    int tok;
    if (mode == 0) {
        tok = src[row * 2 + offset];
    } else if (mode == 1) {
        tok = 0;
    } else {
        float v = partval[(size_t)row * NTILE2 + t];
        int  ix = partidx[(size_t)row * NTILE2 + t];
        #pragma unroll
        for (int off = 1; off < 64; off <<= 1) {
            float ov = __shfl_xor(v, off, 64);
            int   oi = __shfl_xor(ix, off, 64);
            if (ov > v || (ov == v && oi < ix)) { v = ov; ix = oi; }
        }
        tok = ix;
    }
    float2 e = *(const float2*)&table[(size_t)tok * EMB + t * 2];
    ushort2 hh, hl;
    hh.x = f2bf(e.x); hl.x = f2bf(e.x - bf2f(hh.x));
    hh.y = f2bf(e.y); hl.y = f2bf(e.y - bf2f(hh.y));
    *(ushort2*)&Xhi[row * EMB + t * 2] = hh;
    *(ushort2*)&Xlo[row * EMB + t * 2] = hl;
}

// ---------------- weight conversions ----------------
// gate weights: permute rows gate*512+q -> q*4+gate, split hi/lo
__global__ __launch_bounds__(256) void convgate_kernel(
    const float* __restrict__ W, ushort* __restrict__ Whi, ushort* __restrict__ Wlo,
    int kshift)
{
    size_t e0 = ((size_t)blockIdx.x * 256 + threadIdx.x) * 8;
    int K = 1 << kshift;
    int in_row = (int)(e0 >> kshift);
    int q = in_row & 511, gate = in_row >> 9;
    size_t o0 = (((size_t)(q * 4 + gate)) << kshift) + (e0 & (K - 1));
    float4 v0 = *(const float4*)&W[e0];
    float4 v1 = *(const float4*)&W[e0 + 4];
    float x[8] = {v0.x, v0.y, v0.z, v0.w, v1.x, v1.y, v1.z, v1.w};
    uint p[4], qq[4];
    #pragma unroll
    for (int j = 0; j < 4; ++j) {
        ushort h0 = f2bf(x[2 * j]),     l0 = f2bf(x[2 * j] - bf2f(h0));
        ushort h1 = f2bf(x[2 * j + 1]), l1 = f2bf(x[2 * j + 1] - bf2f(h1));
        p[j]  = (uint)h0 | ((uint)h1 << 16);
        qq[j] = (uint)l0 | ((uint)l1 << 16);
    }
    *(uint4*)&Whi[o0] = make_uint4(p[0], p[1], p[2], p[3]);
    *(uint4*)&Wlo[o0] = make_uint4(qq[0], qq[1], qq[2], qq[3]);
}

__global__ __launch_bounds__(256) void convgbias_kernel(
    const float* __restrict__ b0, const float* __restrict__ b1, float* __restrict__ bp)
{
    int i = blockIdx.x * 256 + threadIdx.x;   // G4 threads
    int q = i >> 2, gate = i & 3;
    bp[i] = b0[gate * 512 + q] + b1[gate * 512 + q];
}

// proj weight: padded to VTP2 rows (zeros), split hi/lo
__global__ __launch_bounds__(256) void convw_kernel(
    const float* __restrict__ W, ushort* __restrict__ Whi, ushort* __restrict__ Wlo)
{
    size_t e0 = ((size_t)blockIdx.x * 256 + threadIdx.x) * 8;  // VTP2*HID/8 threads
    int row = (int)(e0 >> 9);
    uint p[4], q[4];
    if (row < VT) {
        float4 v0 = *(const float4*)&W[e0];
        float4 v1 = *(const float4*)&W[e0 + 4];
        float x[8] = {v0.x, v0.y, v0.z, v0.w, v1.x, v1.y, v1.z, v1.w};
        #pragma unroll
        for (int j = 0; j < 4; ++j) {
            ushort h0 = f2bf(x[2 * j]),     l0 = f2bf(x[2 * j] - bf2f(h0));
            ushort h1 = f2bf(x[2 * j + 1]), l1 = f2bf(x[2 * j + 1] - bf2f(h1));
            p[j] = (uint)h0 | ((uint)h1 << 16);
            q[j] = (uint)l0 | ((uint)l1 << 16);
        }
    } else {
        #pragma unroll
        for (int j = 0; j < 4; ++j) { p[j] = 0u; q[j] = 0u; }
    }
    *(uint4*)&Whi[e0] = make_uint4(p[0], p[1], p[2], p[3]);
    *(uint4*)&Wlo[e0] = make_uint4(q[0], q[1], q[2], q[3]);
}

__global__ __launch_bounds__(256) void convb_kernel(
    const float* __restrict__ b, float* __restrict__ bp)
{
    int i = blockIdx.x * 256 + threadIdx.x;
    if (i < VTP2) bp[i] = (i < VT) ? b[i] : -1e30f;
}

// ---------------- fused gates GEMM + LSTM cell ----------------
// Permuted gate layout: col 4q+gate. Block: 128 rows x 128 cols (= 32 q).
// K-loop: nk k-steps (4 for X-only encoder step 0, else 20 = 4 X + 16 H).
__global__ __launch_bounds__(256) void gatescell_kernel(
    const ushort* __restrict__ Xhi, const ushort* __restrict__ Xlo,
    const ushort* __restrict__ Hhi, const ushort* __restrict__ Hlo,
    const ushort* __restrict__ WihH, const ushort* __restrict__ WihL,
    const ushort* __restrict__ WhhH, const ushort* __restrict__ WhhL,
    const float* __restrict__ bperm,
    float* __restrict__ Cst,
    ushort* __restrict__ OHhi, ushort* __restrict__ OHlo,
    int nk)
{
    __shared__ ushort S[2][16384];   // 64 KB double buffer

    const int t = threadIdx.x;
    const int n = blockIdx.x;            // 256 blocks
    const int tile = (n & 7) * 2 + ((n >> 3) & 1);
    const int rb = n >> 4;
    const int bj0 = tile * 128;
    const int bi0 = rb * 128;
    const int il = t & 15;
    const int g  = (t >> 4) & 3;
    const int wid = t >> 6;
    const int lane = t & 63;
    const int wr = wid >> 1, wc = wid & 1;

    int aofs[4], bofs[4];
    #pragma unroll
    for (int m = 0; m < 4; ++m) {
        int r = wr * 64 + m * 16 + il;
        aofs[m] = r * 32 + (((g + (r >> 1)) & 3) << 3);
    }
    #pragma unroll
    for (int nn = 0; nn < 4; ++nn) {
        int r = wc * 64 + nn * 16 + il;
        bofs[nn] = r * 32 + (((g + (r >> 1)) & 3) << 3);
    }

    f32x4 acc[4][4];
    #pragma unroll
    for (int m = 0; m < 4; ++m)
        #pragma unroll
        for (int nn = 0; nn < 4; ++nn) acc[m][nn] = 0.0f;

    // prologue: stage k-step 0 (X segment)
    stage_tile(S[0], Xhi, Xlo, WihH, WihL, bi0, bj0, EMB, 0, wid, lane);
    __syncthreads();

    for (int ks = 0; ks < nk; ++ks) {
        int cur = ks & 1;
        if (ks + 1 < nk) {
            int kn = ks + 1;
            if (kn < 4) stage_tile(S[cur ^ 1], Xhi, Xlo, WihH, WihL, bi0, bj0, EMB, kn * 32, wid, lane);
            else        stage_tile(S[cur ^ 1], Hhi, Hlo, WhhH, WhhL, bi0, bj0, HID, (kn - 4) * 32, wid, lane);
        }
        ushort* Sb = S[cur];
        bf16x8 ah[4], al[4];
        #pragma unroll
        for (int m = 0; m < 4; ++m) {
            ah[m] = *(const bf16x8*)&Sb[aofs[m]];
            al[m] = *(const bf16x8*)&Sb[4096 + aofs[m]];
        }
        #pragma unroll
        for (int nn = 0; nn < 4; ++nn) {
            bf16x8 bh = *(const bf16x8*)&Sb[8192 + bofs[nn]];
            bf16x8 bl = *(const bf16x8*)&Sb[12288 + bofs[nn]];
            #pragma unroll
            for (int m = 0; m < 4; ++m) {
                acc[m][nn] = __builtin_amdgcn_mfma_f32_16x16x32_bf16(ah[m], bh, acc[m][nn], 0, 0, 0);
                acc[m][nn] = __builtin_amdgcn_mfma_f32_16x16x32_bf16(ah[m], bl, acc[m][nn], 0, 0, 0);
                acc[m][nn] = __builtin_amdgcn_mfma_f32_16x16x32_bf16(al[m], bh, acc[m][nn], 0, 0, 0);
            }
        }
        __syncthreads();
    }

    // ---- epilogue: bias -> LDS transpose -> LSTM cell -> C, H hi/lo ----
    float* Tr = (float*)S;   // [32][132]
    float bn[4];
    #pragma unroll
    for (int nn = 0; nn < 4; ++nn) bn[nn] = bperm[bj0 + wc * 64 + nn * 16 + il];

    #pragma unroll
    for (int m = 0; m < 4; ++m) {
        #pragma unroll
        for (int nn = 0; nn < 4; ++nn)
            #pragma unroll
            for (int j = 0; j < 4; ++j)
                Tr[(wr * 16 + g * 4 + j) * 132 + wc * 64 + nn * 16 + il] = acc[m][nn][j] + bn[nn];
        __syncthreads();
        #pragma unroll
        for (int it = 0; it < 4; ++it) {
            int lr2 = it * 8 + (t >> 5);
            int c0 = (t & 31) * 4;
            int row = bi0 + m * 16 + ((lr2 >> 4) << 6) + (lr2 & 15);
            int q = (bj0 + c0) >> 2;
            float4 gv = *(float4*)&Tr[lr2 * 132 + c0];
            float gi = sigm(gv.x), gf = sigm(gv.y), gg = tanhf(gv.z), go = sigm(gv.w);
            size_t o = (size_t)row * HID + q;
            float cnew = gf * Cst[o] + gi * gg;
            float h = go * tanhf(cnew);
            Cst[o] = cnew;
            ushort hh = f2bf(h);
            OHhi[o] = hh;
            OHlo[o] = f2bf(h - bf2f(hh));
        }
        __syncthreads();
    }
}

// ---------------- split-bf16 MFMA projection GEMM ----------------
// logits[2048, VTP2] = H·Wp^T + bias; fused max-pool RMW + argmax partials.
__global__ __launch_bounds__(256) void proj_kernel(
    const ushort* __restrict__ Ahi, const ushort* __restrict__ Alo,
    const ushort* __restrict__ Whi, const ushort* __restrict__ Wlo,
    const float* __restrict__ biasp,
    float* __restrict__ outmax,
    float* __restrict__ partval, int* __restrict__ partidx,
    int mode)
{
    __shared__ ushort S[2][16384];   // 64 KB double buffer

    const int t = threadIdx.x;
    const int n = blockIdx.x;            // 1024 blocks
    const int xcd = n & 7;
    const int j8 = n >> 3;               // 0..127
    const int tile = xcd * 8 + (j8 & 7);
    const int rb = j8 >> 3;              // 0..15
    const int bj0 = tile * 128;
    const int bi0 = rb * 128;
    const int il = t & 15;
    const int g  = (t >> 4) & 3;
    const int wid = t >> 6;
    const int lane = t & 63;
    const int wr = wid >> 1, wc = wid & 1;

    int aofs[4], bofs[4];
    #pragma unroll
    for (int m = 0; m < 4; ++m) {
        int r = wr * 64 + m * 16 + il;
        aofs[m] = r * 32 + (((g + (r >> 1)) & 3) << 3);
    }
    #pragma unroll
    for (int nn = 0; nn < 4; ++nn) {
        int r = wc * 64 + nn * 16 + il;
        bofs[nn] = r * 32 + (((g + (r >> 1)) & 3) << 3);
    }

    f32x4 acc[4][4];
    #pragma unroll
    for (int m = 0; m < 4; ++m)
        #pragma unroll
        for (int nn = 0; nn < 4; ++nn) acc[m][nn] = 0.0f;

    stage_tile(S[0], Ahi, Alo, Whi, Wlo, bi0, bj0, HID, 0, wid, lane);
    __syncthreads();

    for (int ks = 0; ks < 16; ++ks) {
        int cur = ks & 1;
        if (ks + 1 < 16)
            stage_tile(S[cur ^ 1], Ahi, Alo, Whi, Wlo, bi0, bj0, HID, (ks + 1) * 32, wid, lane);
        ushort* Sb = S[cur];
        bf16x8 ah[4], al[4];
        #pragma unroll
        for (int m = 0; m < 4; ++m) {
            ah[m] = *(const bf16x8*)&Sb[aofs[m]];
            al[m] = *(const bf16x8*)&Sb[4096 + aofs[m]];
        }
        #pragma unroll
        for (int nn = 0; nn < 4; ++nn) {
            bf16x8 bh = *(const bf16x8*)&Sb[8192 + bofs[nn]];
            bf16x8 bl = *(const bf16x8*)&Sb[12288 + bofs[nn]];
            #pragma unroll
            for (int m = 0; m < 4; ++m) {
                acc[m][nn] = __builtin_amdgcn_mfma_f32_16x16x32_bf16(ah[m], bh, acc[m][nn], 0, 0, 0);
                acc[m][nn] = __builtin_amdgcn_mfma_f32_16x16x32_bf16(ah[m], bl, acc[m][nn], 0, 0, 0);
                acc[m][nn] = __builtin_amdgcn_mfma_f32_16x16x32_bf16(al[m], bh, acc[m][nn], 0, 0, 0);
            }
        }
        __syncthreads();
    }

    // ---- epilogue: bias, LDS transpose, coalesced float4 RMW + argmax ----
    float* Tr = (float*)S;   // [32][132]
    float bn[4];
    #pragma unroll
    for (int nn = 0; nn < 4; ++nn) bn[nn] = biasp[bj0 + wc * 64 + nn * 16 + il];

    #pragma unroll
    for (int m = 0; m < 4; ++m) {
        #pragma unroll
        for (int nn = 0; nn < 4; ++nn)
            #pragma unroll
            for (int j = 0; j < 4; ++j)
                Tr[(wr * 16 + g * 4 + j) * 132 + wc * 64 + nn * 16 + il] = acc[m][nn][j] + bn[nn];
        __syncthreads();
        #pragma unroll
        for (int it = 0; it < 4; ++it) {
            int lr2 = it * 8 + (t >> 5);
            int c0 = (t & 31) * 4;
            int row = bi0 + m * 16 + ((lr2 >> 4) << 6) + (lr2 & 15);
            int col = bj0 + c0;
            float4 cur = *(float4*)&Tr[lr2 * 132 + c0];

            float bv = cur.x; int bix = col;
            if (cur.y > bv) { bv = cur.y; bix = col + 1; }
            if (cur.z > bv) { bv = cur.z; bix = col + 2; }
            if (cur.w > bv) { bv = cur.w; bix = col + 3; }
            #pragma unroll
            for (int off = 1; off < 32; off <<= 1) {
                float ov = __shfl_xor(bv, off, 64);
                int   oi = __shfl_xor(bix, off, 64);
                if (ov > bv || (ov == bv && oi < bix)) { bv = ov; bix = oi; }
            }
            if ((t & 31) == 0) {
                partval[(size_t)row * NTILE2 + tile] = bv;
                partidx[(size_t)row * NTILE2 + tile] = bix;
            }

            if (col < VT) {
                float* op = &outmax[(size_t)row * VT + col];
                float4 o = cur;
                if (mode == 2) {
                    float4 p = *(const float4*)op;
                    o.x = fmaxf(o.x, p.x); o.y = fmaxf(o.y, p.y);
                    o.z = fmaxf(o.z, p.z); o.w = fmaxf(o.w, p.w);
                }
                *(float4*)op = o;
            }
        }
        __syncthreads();
    }
}

extern "C" void kernel_launch(void* const* d_in, const int* in_sizes, int n_in,
                              void* d_out, int out_size, void* d_ws, size_t ws_size,
                              hipStream_t stream) {
    const int*   src       = (const int*)d_in[0];
    const float* src_embed = (const float*)d_in[1];
    const float* tgt_embed = (const float*)d_in[2];
    const float* enc_Wih   = (const float*)d_in[3];
    const float* enc_Whh   = (const float*)d_in[4];
    const float* enc_bih   = (const float*)d_in[5];
    const float* enc_bhh   = (const float*)d_in[6];
    const float* dec_Wih   = (const float*)d_in[7];
    const float* dec_Whh   = (const float*)d_in[8];
    const float* dec_bih   = (const float*)d_in[9];
    const float* dec_bhh   = (const float*)d_in[10];
    const float* proj_W    = (const float*)d_in[11];
    const float* proj_b    = (const float*)d_in[12];
    float* out = (float*)d_out;

    char* ws = (char*)d_ws;
    float*  C     = (float*)ws;   ws += (size_t)BB * HID * 4;        // 4 MB
    float*  PV    = (float*)ws;   ws += (size_t)BB * NTILE2 * 4;     // 512 KB
    int*    PI    = (int*)ws;     ws += (size_t)BB * NTILE2 * 4;     // 512 KB
    ushort* Xhi   = (ushort*)ws;  ws += (size_t)BB * EMB * 2;
    ushort* Xlo   = (ushort*)ws;  ws += (size_t)BB * EMB * 2;
    ushort* Hhi   = (ushort*)ws;  ws += (size_t)BB * HID * 2;
    ushort* Hlo   = (ushort*)ws;  ws += (size_t)BB * HID * 2;
    ushort* PWhi  = (ushort*)ws;  ws += (size_t)VTP2 * HID * 2;      // 8 MB
    ushort* PWlo  = (ushort*)ws;  ws += (size_t)VTP2 * HID * 2;      // 8 MB
    float*  biasp = (float*)ws;   ws += (size_t)VTP2 * 4;
    ushort* eWihH = (ushort*)ws;  ws += (size_t)G4 * EMB * 2;
    ushort* eWihL = (ushort*)ws;  ws += (size_t)G4 * EMB * 2;
    ushort* eWhhH = (ushort*)ws;  ws += (size_t)G4 * HID * 2;
    ushort* eWhhL = (ushort*)ws;  ws += (size_t)G4 * HID * 2;
    ushort* dWihH = (ushort*)ws;  ws += (size_t)G4 * EMB * 2;
    ushort* dWihL = (ushort*)ws;  ws += (size_t)G4 * EMB * 2;
    ushort* dWhhH = (ushort*)ws;  ws += (size_t)G4 * HID * 2;
    ushort* dWhhL = (ushort*)ws;  ws += (size_t)G4 * HID * 2;
    float*  BSe   = (float*)ws;   ws += (size_t)G4 * 4;
    float*  BSd   = (float*)ws;   ws += (size_t)G4 * 4;

    hipMemsetAsync(C, 0, (size_t)BB * HID * 4, stream);

    // weight conversions (gate weights row-permuted to q*4+gate)
    convw_kernel<<<VTP2 * HID / 8 / 256, 256, 0, stream>>>(proj_W, PWhi, PWlo);
    convb_kernel<<<VTP2 / 256, 256, 0, stream>>>(proj_b, biasp);
    convgate_kernel<<<G4 * EMB / 8 / 256, 256, 0, stream>>>(enc_Wih, eWihH, eWihL, 7);
    convgate_kernel<<<G4 * HID / 8 / 256, 256, 0, stream>>>(enc_Whh, eWhhH, eWhhL, 9);
    convgate_kernel<<<G4 * EMB / 8 / 256, 256, 0, stream>>>(dec_Wih, dWihH, dWihL, 7);
    convgate_kernel<<<G4 * HID / 8 / 256, 256, 0, stream>>>(dec_Whh, dWhhH, dWhhL, 9);
    convgbias_kernel<<<G4 / 256, 256, 0, stream>>>(enc_bih, enc_bhh, BSe);
    convgbias_kernel<<<G4 / 256, 256, 0, stream>>>(dec_bih, dec_bhh, BSd);

    // ---- encoder: 2 steps (step 0 skips the H segment: h == 0) ----
    for (int tstep = 0; tstep < 2; ++tstep) {
        gather2_kernel<<<BB, 64, 0, stream>>>(Xhi, Xlo, src_embed, src, 0, tstep, PV, PI);
        gatescell_kernel<<<256, 256, 0, stream>>>(Xhi, Xlo, Hhi, Hlo,
            eWihH, eWihL, eWhhH, eWhhL, BSe, C, Hhi, Hlo, tstep == 0 ? 4 : 20);
    }

    // ---- decoder: 9 greedy steps ----
    for (int s = 0; s < NSTEP; ++s) {
        gather2_kernel<<<BB, 64, 0, stream>>>(Xhi, Xlo, tgt_embed, nullptr,
            (s == 0 ? 1 : 2), 0, PV, PI);
        gatescell_kernel<<<256, 256, 0, stream>>>(Xhi, Xlo, Hhi, Hlo,
            dWihH, dWihL, dWhhH, dWhhL, BSd, C, Hhi, Hlo, 20);
        proj_kernel<<<1024, 256, 0, stream>>>(Hhi, Hlo, PWhi, PWlo, biasp,
            out, PV, PI, (s == 0 ? 1 : 2));
    }
}